// Round 9
// baseline (314.672 us; speedup 1.0000x reference)
//
#include <hip/hip_runtime.h>

#define N_NODES 65536
#define N_EDGES 262144
#define N_GRAPH 256
#define DV 256
#define DE 128
#define DG 256
#define EPS 1e-5f

typedef __bf16 bf16_t;
typedef bf16_t bf16x8 __attribute__((ext_vector_type(8)));
typedef float f32x4 __attribute__((ext_vector_type(4)));
typedef unsigned short ushort_t;

__device__ __forceinline__ float silu_f(float x) {
  return x / (1.0f + __expf(-x));
}
__device__ __forceinline__ unsigned short f2bf(float f) {
  unsigned int u = __float_as_uint(f);
  u += 0x7fffu + ((u >> 16) & 1u);  // RTNE
  return (unsigned short)(u >> 16);
}
__device__ __forceinline__ float bf2f(unsigned short h) {
  return __uint_as_float(((unsigned int)h) << 16);
}
__device__ __forceinline__ void split_bf(float x, ushort_t& hi, ushort_t& lo) {
  hi = f2bf(x);
  lo = f2bf(x - bf2f(hi));
}
__device__ __forceinline__ void wave_reduce2(float& s1, float& s2) {
  #pragma unroll
  for (int off = 32; off > 0; off >>= 1) {
    s1 += __shfl_xor(s1, off);
    s2 += __shfl_xor(s2, off);
  }
}

// ---------------- prep: convert weights f32 -> bf16 (row-major [N][K]) -----
__global__ __launch_bounds__(256) void k_prep(
    const float* __restrict__ W_v, const float* __restrict__ W_e,
    const float* __restrict__ W_vpos, ushort_t* __restrict__ Wv_bf,
    ushort_t* __restrict__ We_bf, ushort_t* __restrict__ Wvpos_bf) {
  int idx = blockIdx.x * 256 + threadIdx.x;  // float4 group id, 49152 total
  const float* s;
  ushort_t* d;
  int o;
  if (idx < 32768) { s = W_v; d = Wv_bf; o = idx; }
  else if (idx < 40960) { s = W_e; d = We_bf; o = idx - 32768; }
  else { s = W_vpos; d = Wvpos_bf; o = idx - 40960; }
  float4 v = *(const float4*)&s[(size_t)o * 4];
  ushort4 r;
  r.x = f2bf(v.x); r.y = f2bf(v.y); r.z = f2bf(v.z); r.w = f2bf(v.w);
  *(ushort4*)&d[(size_t)o * 4] = r;
}

// ---------------- fvp = fv_pos_c @ W_vpos^T + b  -> bf16 [N,128] -----------
// M-tile 32, 8 waves: wave w -> rows (w&1)*16, cols (w>>1)*32
__global__ __launch_bounds__(512) void k_fvp(
    const float* __restrict__ fv_pos_c, const ushort_t* __restrict__ Wvpos_bf,
    const float* __restrict__ b_vpos, ushort_t* __restrict__ fvp_bf) {
  __shared__ __align__(16) ushort_t Xh[32][264];
  __shared__ __align__(16) ushort_t Xl[32][264];
  const int tid = threadIdx.x;
  const int l = tid & 63, w = tid >> 6;
  const int m0 = blockIdx.x * 32;
  #pragma unroll
  for (int i = 0; i < 4; ++i) {
    int idx = i * 512 + tid;          // 0..2047
    int r = idx >> 6, c4 = idx & 63;  // 32 rows x 64 groups
    float4 v = *(const float4*)&fv_pos_c[(size_t)(m0 + r) * DV + c4 * 4];
    ushort4 h, lo;
    split_bf(v.x, h.x, lo.x);
    split_bf(v.y, h.y, lo.y);
    split_bf(v.z, h.z, lo.z);
    split_bf(v.w, h.w, lo.w);
    *(ushort4*)&Xh[r][c4 * 4] = h;
    *(ushort4*)&Xl[r][c4 * 4] = lo;
  }
  __syncthreads();
  f32x4 acc[2];
  acc[0] = (f32x4)(0.f);
  acc[1] = (f32x4)(0.f);
  const int mrow = (w & 1) * 16;
  const int ncol0 = (w >> 1) * 32;
  const int arow = mrow + (l & 15);
  for (int kc = 0; kc < 8; ++kc) {
    int ke = kc * 32 + (l >> 4) * 8;
    bf16x8 ah = *(const bf16x8*)&Xh[arow][ke];
    bf16x8 al = *(const bf16x8*)&Xl[arow][ke];
    #pragma unroll
    for (int ni = 0; ni < 2; ++ni) {
      bf16x8 b = *(const bf16x8*)&Wvpos_bf[(size_t)(ncol0 + ni * 16 + (l & 15)) * DV + ke];
      acc[ni] = __builtin_amdgcn_mfma_f32_16x16x32_bf16(al, b, acc[ni], 0, 0, 0);
      acc[ni] = __builtin_amdgcn_mfma_f32_16x16x32_bf16(ah, b, acc[ni], 0, 0, 0);
    }
  }
  #pragma unroll
  for (int ni = 0; ni < 2; ++ni) {
    int col = ncol0 + ni * 16 + (l & 15);
    float bias = b_vpos[col];
    #pragma unroll
    for (int j = 0; j < 4; ++j) {
      int row = m0 + mrow + (l >> 4) * 4 + j;
      fvp_bf[(size_t)row * DE + col] = f2bf(acc[ni][j] + bias);
    }
  }
}

// ====== fused node+edge kernel ============================================
// bid%3==0 -> node tile g3=bid/3 (2048 tiles of M=32)
// else     -> edge tile eid=(bid/3)*2+(bid%3-1) (4096 tiles of M=64)
__global__ __launch_bounds__(512) void k_node_edge(
    const float* __restrict__ fv, const float* __restrict__ fv_c,
    const float* __restrict__ fv_pos_c, const ushort_t* __restrict__ Wv_bf,
    const float* __restrict__ b_v, float* __restrict__ fv_out,
    const float* __restrict__ fe, const float* __restrict__ fe_c,
    const ushort_t* __restrict__ fvp_bf, const int* __restrict__ src,
    const int* __restrict__ dst, const ushort_t* __restrict__ We_bf,
    const float* __restrict__ b_e, float* __restrict__ fe_out) {
  __shared__ __align__(16) char smem[35328];
  const int bid = blockIdx.x;
  const int g3 = bid / 3, r3 = bid % 3;
  const int tid = threadIdx.x;
  const int l = tid & 63, w = tid >> 6;
  if (r3 == 0) {
    // ------------------ node block: VERBATIM R7 k_node ------------------
    ushort_t (*Xh)[264] = (ushort_t(*)[264])smem;
    ushort_t (*Xl)[264] = (ushort_t(*)[264])(smem + 16896);
    float* muL = (float*)(smem + 33792);
    float* rsL = (float*)(smem + 33920);
    const int m0 = g3 * 32;
    // stage X = silu(fv_c + fv_pos_c) as hi/lo bf16
    #pragma unroll
    for (int i = 0; i < 4; ++i) {
      int idx = i * 512 + tid;
      int r = idx >> 6, c4 = idx & 63;
      size_t g = (size_t)(m0 + r) * DV + c4 * 4;
      float4 a = *(const float4*)&fv_c[g];
      float4 b = *(const float4*)&fv_pos_c[g];
      ushort4 h, lo;
      split_bf(silu_f(a.x + b.x), h.x, lo.x);
      split_bf(silu_f(a.y + b.y), h.y, lo.y);
      split_bf(silu_f(a.z + b.z), h.z, lo.z);
      split_bf(silu_f(a.w + b.w), h.w, lo.w);
      *(ushort4*)&Xh[r][c4 * 4] = h;
      *(ushort4*)&Xl[r][c4 * 4] = lo;
    }
    // LN stats: wave w handles rows w*4..+3
    #pragma unroll
    for (int rr = 0; rr < 4; ++rr) {
      int row = w * 4 + rr;
      float4 v = *(const float4*)&fv[(size_t)(m0 + row) * DV + l * 4];
      float s1 = v.x + v.y + v.z + v.w;
      float s2 = v.x * v.x + v.y * v.y + v.z * v.z + v.w * v.w;
      wave_reduce2(s1, s2);
      if (l == 0) {
        float mu = s1 * (1.0f / DV);
        float var = s2 * (1.0f / DV) - mu * mu;
        muL[row] = mu;
        rsL[row] = rsqrtf(var + EPS);
      }
    }
    __syncthreads();
    f32x4 acc[2][4];  // [mi][ni]: ni 0,1 = shift tiles, ni 2,3 = scale tiles
    #pragma unroll
    for (int mi = 0; mi < 2; ++mi)
      #pragma unroll
      for (int ni = 0; ni < 4; ++ni) acc[mi][ni] = (f32x4)(0.f);
    int ncol[4];
    ncol[0] = w * 32;
    ncol[1] = w * 32 + 16;
    ncol[2] = DV + w * 32;
    ncol[3] = DV + w * 32 + 16;
    for (int kc = 0; kc < 8; ++kc) {
      int ke = kc * 32 + (l >> 4) * 8;
      bf16x8 ah[2], al[2];
      #pragma unroll
      for (int mi = 0; mi < 2; ++mi) {
        ah[mi] = *(const bf16x8*)&Xh[mi * 16 + (l & 15)][ke];
        al[mi] = *(const bf16x8*)&Xl[mi * 16 + (l & 15)][ke];
      }
      #pragma unroll
      for (int ni = 0; ni < 4; ++ni) {
        bf16x8 b = *(const bf16x8*)&Wv_bf[(size_t)(ncol[ni] + (l & 15)) * DV + ke];
        #pragma unroll
        for (int mi = 0; mi < 2; ++mi) {
          acc[mi][ni] = __builtin_amdgcn_mfma_f32_16x16x32_bf16(al[mi], b, acc[mi][ni], 0, 0, 0);
          acc[mi][ni] = __builtin_amdgcn_mfma_f32_16x16x32_bf16(ah[mi], b, acc[mi][ni], 0, 0, 0);
        }
      }
    }
    // epilogue: in-register modulation
    #pragma unroll
    for (int ni2 = 0; ni2 < 2; ++ni2) {
      int c = w * 32 + ni2 * 16 + (l & 15);
      float bsh = b_v[c];
      float bsc = b_v[DV + c];
      #pragma unroll
      for (int mi = 0; mi < 2; ++mi)
        #pragma unroll
        for (int j = 0; j < 4; ++j) {
          int row = mi * 16 + (l >> 4) * 4 + j;
          size_t g = (size_t)(m0 + row) * DV + c;
          float v = fv[g];
          float sh = acc[mi][ni2][j] + bsh;
          float sc = acc[mi][ni2 + 2][j] + bsc;
          fv_out[g] = (v - muL[row]) * rsL[row] * (1.0f + sc) + sh;
        }
    }
  } else {
    // ------------------ edge block: VERBATIM R7 k_edge ------------------
    ushort_t (*Xh)[136] = (ushort_t(*)[136])smem;
    ushort_t (*Xl)[136] = (ushort_t(*)[136])(smem + 17408);
    float* muL = (float*)(smem + 34816);
    float* rsL = (float*)(smem + 35072);
    const int m0 = (g3 * 2 + (r3 - 1)) * 64;
    const int sub = l & 15, quad = l >> 4;
    // stage X = silu(fe_c + fvp[src] + fvp[dst]) as hi/lo bf16
    #pragma unroll
    for (int i = 0; i < 4; ++i) {
      int idx = i * 512 + tid;          // 0..2047
      int r = idx >> 5, c4 = idx & 31;  // 64 rows x 32 groups
      int sr = src[m0 + r], dr = dst[m0 + r];
      float4 a = *(const float4*)&fe_c[(size_t)(m0 + r) * DE + c4 * 4];
      ushort4 p = *(const ushort4*)&fvp_bf[(size_t)sr * DE + c4 * 4];
      ushort4 q = *(const ushort4*)&fvp_bf[(size_t)dr * DE + c4 * 4];
      ushort4 h, lo;
      split_bf(silu_f(a.x + bf2f(p.x) + bf2f(q.x)), h.x, lo.x);
      split_bf(silu_f(a.y + bf2f(p.y) + bf2f(q.y)), h.y, lo.y);
      split_bf(silu_f(a.z + bf2f(p.z) + bf2f(q.z)), h.z, lo.z);
      split_bf(silu_f(a.w + bf2f(p.w) + bf2f(q.w)), h.w, lo.w);
      *(ushort4*)&Xh[r][c4 * 4] = h;
      *(ushort4*)&Xl[r][c4 * 4] = lo;
    }
    // LN stats (quad-based, R5 numerics): wave w -> rows w*8..+7
    #pragma unroll
    for (int j2 = 0; j2 < 2; ++j2) {
      int row = w * 8 + quad * 2 + j2;
      float s1 = 0.f, s2 = 0.f;
      #pragma unroll
      for (int ci = 0; ci < 8; ++ci) {
        float v = fe[(size_t)(m0 + row) * DE + ci * 16 + sub];
        s1 += v;
        s2 += v * v;
      }
      #pragma unroll
      for (int off = 1; off < 16; off <<= 1) {
        s1 += __shfl_xor(s1, off);
        s2 += __shfl_xor(s2, off);
      }
      if (sub == 0) {
        float m = s1 * (1.0f / DE);
        float var = s2 * (1.0f / DE) - m * m;
        muL[row] = m;
        rsL[row] = rsqrtf(var + EPS);
      }
    }
    __syncthreads();
    f32x4 acc[4][2];  // [mi][ni]: ni 0 = shift tile, ni 1 = scale tile
    #pragma unroll
    for (int mi = 0; mi < 4; ++mi) {
      acc[mi][0] = (f32x4)(0.f);
      acc[mi][1] = (f32x4)(0.f);
    }
    for (int kc = 0; kc < 4; ++kc) {
      int ke = kc * 32 + quad * 8;
      bf16x8 ah[4], al[4];
      #pragma unroll
      for (int mi = 0; mi < 4; ++mi) {
        ah[mi] = *(const bf16x8*)&Xh[mi * 16 + sub][ke];
        al[mi] = *(const bf16x8*)&Xl[mi * 16 + sub][ke];
      }
      #pragma unroll
      for (int ni = 0; ni < 2; ++ni) {
        bf16x8 b = *(const bf16x8*)&We_bf[(size_t)(ni * DE + w * 16 + sub) * DE + ke];
        #pragma unroll
        for (int mi = 0; mi < 4; ++mi) {
          acc[mi][ni] = __builtin_amdgcn_mfma_f32_16x16x32_bf16(al[mi], b, acc[mi][ni], 0, 0, 0);
          acc[mi][ni] = __builtin_amdgcn_mfma_f32_16x16x32_bf16(ah[mi], b, acc[mi][ni], 0, 0, 0);
        }
      }
    }
    // epilogue
    {
      int c = w * 16 + sub;
      float bsh = b_e[c];
      float bsc = b_e[DE + c];
      #pragma unroll
      for (int mi = 0; mi < 4; ++mi)
        #pragma unroll
        for (int j = 0; j < 4; ++j) {
          int row = mi * 16 + quad * 4 + j;
          size_t g = (size_t)(m0 + row) * DE + c;
          float v = fe[g];
          float sh = acc[mi][0][j] + bsh;
          float sc = acc[mi][1][j] + bsc;
          fe_out[g] = (v - muL[row]) * rsL[row] * (1.0f + sc) + sh;
        }
    }
  }
}

// ------ fused per-graph kernel: fg LN + s, pos segment-norm + out ---------
__global__ __launch_bounds__(256) void k_fg_pos(
    const float* __restrict__ fg, const float* __restrict__ g_gamma,
    const float* __restrict__ g_beta, const float* __restrict__ W_pos,
    const float* __restrict__ b_pos, const float* __restrict__ fv_pos,
    const int* __restrict__ node_gid, float* __restrict__ fg_out,
    float* __restrict__ pos_out) {
  const int g = blockIdx.x, t = threadIdx.x;
  const int lane = t & 63, wave = t >> 6;
  __shared__ float p1[4], p2[4], p3[4];
  __shared__ float px[4], py[4], pz[4], pq[4];
  // ---- graph LN + s ----
  float x = fg[g * DG + t];
  float sv = silu_f(x) * W_pos[t];
  float s1 = x, s2 = x * x, s3 = sv;
  #pragma unroll
  for (int off = 32; off > 0; off >>= 1) {
    s1 += __shfl_xor(s1, off);
    s2 += __shfl_xor(s2, off);
    s3 += __shfl_xor(s3, off);
  }
  if (lane == 0) { p1[wave] = s1; p2[wave] = s2; p3[wave] = s3; }
  __syncthreads();
  s1 = p1[0] + p1[1] + p1[2] + p1[3];
  s2 = p2[0] + p2[1] + p2[2] + p2[3];
  float mu = s1 * (1.0f / DG);
  float var = s2 * (1.0f / DG) - mu * mu;
  float rstd = rsqrtf(var + EPS);
  fg_out[g * DG + t] = (x - mu) * rstd * g_gamma[t] + g_beta[t];
  float s_own = (p3[0] + p3[1] + p3[2] + p3[3]) + b_pos[0];  // s for graph g
  // ---- position ----
  const int i = g * 256 + t;
  const int gid = node_gid[i];
  float vx = fv_pos[3 * i + 0];
  float vy = fv_pos[3 * i + 1];
  float vz = fv_pos[3 * i + 2];
  if (__syncthreads_and(gid == g)) {
    float rx = vx, ry = vy, rz = vz, rq = vx * vx + vy * vy + vz * vz;
    #pragma unroll
    for (int off = 32; off > 0; off >>= 1) {
      rx += __shfl_xor(rx, off);
      ry += __shfl_xor(ry, off);
      rz += __shfl_xor(rz, off);
      rq += __shfl_xor(rq, off);
    }
    if (lane == 0) { px[wave] = rx; py[wave] = ry; pz[wave] = rz; pq[wave] = rq; }
    __syncthreads();
    float sx = px[0] + px[1] + px[2] + px[3];
    float sy = py[0] + py[1] + py[2] + py[3];
    float sz = pz[0] + pz[1] + pz[2] + pz[3];
    float sq = pq[0] + pq[1] + pq[2] + pq[3];
    float ic = 1.0f / 256.0f;
    float mx = sx * ic, my = sy * ic, mz = sz * ic;
    float cq = fmaxf(sq - 256.0f * (mx * mx + my * my + mz * mz), 0.0f);
    float rms = sqrtf(cq / (256.0f * 3.0f) + EPS);
    float sc = (1.0f + s_own) / rms;
    pos_out[3 * i + 0] = (vx - mx) * sc;
    pos_out[3 * i + 1] = (vy - my) * sc;
    pos_out[3 * i + 2] = (vz - mz) * sc;
  } else {
    // slow but fully general fallback: scan all nodes of this thread's graph
    float sx = 0.f, sy = 0.f, sz = 0.f, sq = 0.f, cnt = 0.f;
    for (int j = 0; j < N_NODES; ++j) {
      if (node_gid[j] == gid) {
        float ax = fv_pos[3 * j + 0];
        float ay = fv_pos[3 * j + 1];
        float az = fv_pos[3 * j + 2];
        sx += ax; sy += ay; sz += az;
        sq += ax * ax + ay * ay + az * az;
        cnt += 1.0f;
      }
    }
    float ic = 1.0f / fmaxf(cnt, 1.0f);
    float mx = sx * ic, my = sy * ic, mz = sz * ic;
    float cq = fmaxf(sq - cnt * (mx * mx + my * my + mz * mz), 0.0f);
    float rms = sqrtf(cq / (cnt * 3.0f) + EPS);
    float sg = 0.f;
    for (int c = 0; c < DG; ++c) sg += silu_f(fg[gid * DG + c]) * W_pos[c];
    float sc = (1.0f + sg + b_pos[0]) / rms;
    pos_out[3 * i + 0] = (vx - mx) * sc;
    pos_out[3 * i + 1] = (vy - my) * sc;
    pos_out[3 * i + 2] = (vz - mz) * sc;
  }
}

extern "C" void kernel_launch(void* const* d_in, const int* in_sizes, int n_in,
                              void* d_out, int out_size, void* d_ws,
                              size_t ws_size, hipStream_t stream) {
  const float* fv = (const float*)d_in[0];
  const float* fe = (const float*)d_in[1];
  const float* fg = (const float*)d_in[2];
  const float* fv_pos = (const float*)d_in[3];
  const float* fv_c = (const float*)d_in[4];
  const float* fe_c = (const float*)d_in[5];
  const float* fv_pos_c = (const float*)d_in[6];
  const float* W_v = (const float*)d_in[7];
  const float* b_v = (const float*)d_in[8];
  const float* W_vpos = (const float*)d_in[9];
  const float* b_vpos = (const float*)d_in[10];
  const float* W_e = (const float*)d_in[11];
  const float* b_e = (const float*)d_in[12];
  const float* g_gamma = (const float*)d_in[13];
  const float* g_beta = (const float*)d_in[14];
  const float* W_pos = (const float*)d_in[15];
  const float* b_pos = (const float*)d_in[16];
  const int* src = (const int*)d_in[17];
  const int* dst = (const int*)d_in[18];
  const int* node_gid = (const int*)d_in[19];

  float* out = (float*)d_out;
  float* fv_out = out;
  float* fe_out = fv_out + (size_t)N_NODES * DV;
  float* fg_out = fe_out + (size_t)N_EDGES * DE;
  float* pos_out = fg_out + (size_t)N_GRAPH * DG;

  char* ws = (char*)d_ws;
  ushort_t* fvp_bf = (ushort_t*)ws;                                  // 16.8 MB
  ushort_t* Wv_bf = (ushort_t*)(ws + 16777216);                      // 256 KB
  ushort_t* We_bf = (ushort_t*)(ws + 16777216 + 262144);             // 64 KB
  ushort_t* Wvpos_bf = (ushort_t*)(ws + 16777216 + 262144 + 65536);  // 64 KB

  k_prep<<<192, 256, 0, stream>>>(W_v, W_e, W_vpos, Wv_bf, We_bf, Wvpos_bf);
  k_fvp<<<N_NODES / 32, 512, 0, stream>>>(fv_pos_c, Wvpos_bf, b_vpos, fvp_bf);
  k_node_edge<<<6144, 512, 0, stream>>>(fv, fv_c, fv_pos_c, Wv_bf, b_v, fv_out,
                                        fe, fe_c, fvp_bf, src, dst, We_bf,
                                        b_e, fe_out);
  k_fg_pos<<<N_GRAPH, 256, 0, stream>>>(fg, g_gamma, g_beta, W_pos, b_pos,
                                        fv_pos, node_gid, fg_out, pos_out);
}

// Round 10
// 284.996 us; speedup vs baseline: 1.1041x; 1.1041x over previous
//
#include <hip/hip_runtime.h>

#define N_NODES 65536
#define N_EDGES 262144
#define N_GRAPH 256
#define DV 256
#define DE 128
#define DG 256
#define EPS 1e-5f

typedef __bf16 bf16_t;
typedef bf16_t bf16x8 __attribute__((ext_vector_type(8)));
typedef float f32x4 __attribute__((ext_vector_type(4)));
typedef unsigned short ushort_t;

__device__ __forceinline__ float silu_f(float x) {
  return x / (1.0f + __expf(-x));
}
__device__ __forceinline__ unsigned short f2bf(float f) {
  unsigned int u = __float_as_uint(f);
  u += 0x7fffu + ((u >> 16) & 1u);  // RTNE
  return (unsigned short)(u >> 16);
}
__device__ __forceinline__ float bf2f(unsigned short h) {
  return __uint_as_float(((unsigned int)h) << 16);
}
__device__ __forceinline__ void split_bf(float x, ushort_t& hi, ushort_t& lo) {
  hi = f2bf(x);
  lo = f2bf(x - bf2f(hi));
}
__device__ __forceinline__ void wave_reduce2(float& s1, float& s2) {
  #pragma unroll
  for (int off = 32; off > 0; off >>= 1) {
    s1 += __shfl_xor(s1, off);
    s2 += __shfl_xor(s2, off);
  }
}

// ---------------- prep: convert weights f32 -> bf16 (row-major [N][K]) -----
__global__ __launch_bounds__(256) void k_prep(
    const float* __restrict__ W_v, const float* __restrict__ W_e,
    const float* __restrict__ W_vpos, ushort_t* __restrict__ Wv_bf,
    ushort_t* __restrict__ We_bf, ushort_t* __restrict__ Wvpos_bf) {
  int idx = blockIdx.x * 256 + threadIdx.x;  // float4 group id, 49152 total
  const float* s;
  ushort_t* d;
  int o;
  if (idx < 32768) { s = W_v; d = Wv_bf; o = idx; }
  else if (idx < 40960) { s = W_e; d = We_bf; o = idx - 32768; }
  else { s = W_vpos; d = Wvpos_bf; o = idx - 40960; }
  float4 v = *(const float4*)&s[(size_t)o * 4];
  ushort4 r;
  r.x = f2bf(v.x); r.y = f2bf(v.y); r.z = f2bf(v.z); r.w = f2bf(v.w);
  *(ushort4*)&d[(size_t)o * 4] = r;
}

// ---------------- fvp = fv_pos_c @ W_vpos^T + b  -> bf16 [N,128] -----------
// M-tile 32, 8 waves: wave w -> rows (w&1)*16, cols (w>>1)*32
__global__ __launch_bounds__(512) void k_fvp(
    const float* __restrict__ fv_pos_c, const ushort_t* __restrict__ Wvpos_bf,
    const float* __restrict__ b_vpos, ushort_t* __restrict__ fvp_bf) {
  __shared__ __align__(16) ushort_t Xh[32][264];
  __shared__ __align__(16) ushort_t Xl[32][264];
  const int tid = threadIdx.x;
  const int l = tid & 63, w = tid >> 6;
  const int m0 = blockIdx.x * 32;
  #pragma unroll
  for (int i = 0; i < 4; ++i) {
    int idx = i * 512 + tid;          // 0..2047
    int r = idx >> 6, c4 = idx & 63;  // 32 rows x 64 groups
    float4 v = *(const float4*)&fv_pos_c[(size_t)(m0 + r) * DV + c4 * 4];
    ushort4 h, lo;
    split_bf(v.x, h.x, lo.x);
    split_bf(v.y, h.y, lo.y);
    split_bf(v.z, h.z, lo.z);
    split_bf(v.w, h.w, lo.w);
    *(ushort4*)&Xh[r][c4 * 4] = h;
    *(ushort4*)&Xl[r][c4 * 4] = lo;
  }
  __syncthreads();
  f32x4 acc[2];
  acc[0] = (f32x4)(0.f);
  acc[1] = (f32x4)(0.f);
  const int mrow = (w & 1) * 16;
  const int ncol0 = (w >> 1) * 32;
  const int arow = mrow + (l & 15);
  for (int kc = 0; kc < 8; ++kc) {
    int ke = kc * 32 + (l >> 4) * 8;
    bf16x8 ah = *(const bf16x8*)&Xh[arow][ke];
    bf16x8 al = *(const bf16x8*)&Xl[arow][ke];
    #pragma unroll
    for (int ni = 0; ni < 2; ++ni) {
      bf16x8 b = *(const bf16x8*)&Wvpos_bf[(size_t)(ncol0 + ni * 16 + (l & 15)) * DV + ke];
      acc[ni] = __builtin_amdgcn_mfma_f32_16x16x32_bf16(al, b, acc[ni], 0, 0, 0);
      acc[ni] = __builtin_amdgcn_mfma_f32_16x16x32_bf16(ah, b, acc[ni], 0, 0, 0);
    }
  }
  #pragma unroll
  for (int ni = 0; ni < 2; ++ni) {
    int col = ncol0 + ni * 16 + (l & 15);
    float bias = b_vpos[col];
    #pragma unroll
    for (int j = 0; j < 4; ++j) {
      int row = m0 + mrow + (l >> 4) * 4 + j;
      fvp_bf[(size_t)row * DE + col] = f2bf(acc[ni][j] + bias);
    }
  }
}

// ------- node path: mod_v MFMA GEMM fused with LN(fv) -> fv_out -----------
// M-tile 32, N=512, K=256. Wave w owns shift cols [w*32,+32) AND scale cols
// [256+w*32,+32) so modulation is applied fully in-register. (VERBATIM R7)
__global__ __launch_bounds__(512) void k_node(
    const float* __restrict__ fv, const float* __restrict__ fv_c,
    const float* __restrict__ fv_pos_c, const ushort_t* __restrict__ Wv_bf,
    const float* __restrict__ b_v, float* __restrict__ fv_out) {
  __shared__ __align__(16) ushort_t Xh[32][264];
  __shared__ __align__(16) ushort_t Xl[32][264];
  __shared__ float muL[32], rsL[32];
  const int tid = threadIdx.x;
  const int l = tid & 63, w = tid >> 6;
  const int m0 = blockIdx.x * 32;
  // stage X = silu(fv_c + fv_pos_c) as hi/lo bf16
  #pragma unroll
  for (int i = 0; i < 4; ++i) {
    int idx = i * 512 + tid;
    int r = idx >> 6, c4 = idx & 63;
    size_t g = (size_t)(m0 + r) * DV + c4 * 4;
    float4 a = *(const float4*)&fv_c[g];
    float4 b = *(const float4*)&fv_pos_c[g];
    ushort4 h, lo;
    split_bf(silu_f(a.x + b.x), h.x, lo.x);
    split_bf(silu_f(a.y + b.y), h.y, lo.y);
    split_bf(silu_f(a.z + b.z), h.z, lo.z);
    split_bf(silu_f(a.w + b.w), h.w, lo.w);
    *(ushort4*)&Xh[r][c4 * 4] = h;
    *(ushort4*)&Xl[r][c4 * 4] = lo;
  }
  // LN stats: wave w handles rows w*4..+3
  #pragma unroll
  for (int rr = 0; rr < 4; ++rr) {
    int row = w * 4 + rr;
    float4 v = *(const float4*)&fv[(size_t)(m0 + row) * DV + l * 4];
    float s1 = v.x + v.y + v.z + v.w;
    float s2 = v.x * v.x + v.y * v.y + v.z * v.z + v.w * v.w;
    wave_reduce2(s1, s2);
    if (l == 0) {
      float mu = s1 * (1.0f / DV);
      float var = s2 * (1.0f / DV) - mu * mu;
      muL[row] = mu;
      rsL[row] = rsqrtf(var + EPS);
    }
  }
  __syncthreads();
  f32x4 acc[2][4];  // [mi][ni]: ni 0,1 = shift tiles, ni 2,3 = scale tiles
  #pragma unroll
  for (int mi = 0; mi < 2; ++mi)
    #pragma unroll
    for (int ni = 0; ni < 4; ++ni) acc[mi][ni] = (f32x4)(0.f);
  int ncol[4];
  ncol[0] = w * 32;
  ncol[1] = w * 32 + 16;
  ncol[2] = DV + w * 32;
  ncol[3] = DV + w * 32 + 16;
  for (int kc = 0; kc < 8; ++kc) {
    int ke = kc * 32 + (l >> 4) * 8;
    bf16x8 ah[2], al[2];
    #pragma unroll
    for (int mi = 0; mi < 2; ++mi) {
      ah[mi] = *(const bf16x8*)&Xh[mi * 16 + (l & 15)][ke];
      al[mi] = *(const bf16x8*)&Xl[mi * 16 + (l & 15)][ke];
    }
    #pragma unroll
    for (int ni = 0; ni < 4; ++ni) {
      bf16x8 b = *(const bf16x8*)&Wv_bf[(size_t)(ncol[ni] + (l & 15)) * DV + ke];
      #pragma unroll
      for (int mi = 0; mi < 2; ++mi) {
        acc[mi][ni] = __builtin_amdgcn_mfma_f32_16x16x32_bf16(al[mi], b, acc[mi][ni], 0, 0, 0);
        acc[mi][ni] = __builtin_amdgcn_mfma_f32_16x16x32_bf16(ah[mi], b, acc[mi][ni], 0, 0, 0);
      }
    }
  }
  // epilogue: in-register modulation
  #pragma unroll
  for (int ni2 = 0; ni2 < 2; ++ni2) {
    int c = w * 32 + ni2 * 16 + (l & 15);
    float bsh = b_v[c];
    float bsc = b_v[DV + c];
    #pragma unroll
    for (int mi = 0; mi < 2; ++mi)
      #pragma unroll
      for (int j = 0; j < 4; ++j) {
        int row = mi * 16 + (l >> 4) * 4 + j;
        size_t g = (size_t)(m0 + row) * DV + c;
        float v = fv[g];
        float sh = acc[mi][ni2][j] + bsh;
        float sc = acc[mi][ni2 + 2][j] + bsc;
        fv_out[g] = (v - muL[row]) * rsL[row] * (1.0f + sc) + sh;
      }
  }
}

// ------- edge path: gather + mod_e MFMA GEMM fused with LN(fe) ------------
// M-tile 32 (was 64 in R7), N=256, K=128, 8 waves. Wave w owns shift cols
// [w*16,+16) and scale cols [128+w*16,+16); 2 M-frags per wave. Shorter
// per-block critical path + 2x blocks to hide the fvp gather latency.
// Per-row numerics identical to R7 (same 8-scalar + 16-lane reduce, same
// MFMA order per output).
__global__ __launch_bounds__(512) void k_edge(
    const float* __restrict__ fe, const float* __restrict__ fe_c,
    const ushort_t* __restrict__ fvp_bf, const int* __restrict__ src,
    const int* __restrict__ dst, const ushort_t* __restrict__ We_bf,
    const float* __restrict__ b_e, float* __restrict__ fe_out) {
  __shared__ __align__(16) ushort_t Xh[32][136];
  __shared__ __align__(16) ushort_t Xl[32][136];
  __shared__ float muL[32], rsL[32];
  const int tid = threadIdx.x;
  const int l = tid & 63, w = tid >> 6;
  const int m0 = blockIdx.x * 32;
  const int sub = l & 15, quad = l >> 4;
  // stage X = silu(fe_c + fvp[src] + fvp[dst]) as hi/lo bf16
  #pragma unroll
  for (int i = 0; i < 2; ++i) {
    int idx = i * 512 + tid;          // 0..1023
    int r = idx >> 5, c4 = idx & 31;  // 32 rows x 32 groups
    int sr = src[m0 + r], dr = dst[m0 + r];
    float4 a = *(const float4*)&fe_c[(size_t)(m0 + r) * DE + c4 * 4];
    ushort4 p = *(const ushort4*)&fvp_bf[(size_t)sr * DE + c4 * 4];
    ushort4 q = *(const ushort4*)&fvp_bf[(size_t)dr * DE + c4 * 4];
    ushort4 h, lo;
    split_bf(silu_f(a.x + bf2f(p.x) + bf2f(q.x)), h.x, lo.x);
    split_bf(silu_f(a.y + bf2f(p.y) + bf2f(q.y)), h.y, lo.y);
    split_bf(silu_f(a.z + bf2f(p.z) + bf2f(q.z)), h.z, lo.z);
    split_bf(silu_f(a.w + bf2f(p.w) + bf2f(q.w)), h.w, lo.w);
    *(ushort4*)&Xh[r][c4 * 4] = h;
    *(ushort4*)&Xl[r][c4 * 4] = lo;
  }
  // LN stats (quad-based, R5/R7 numerics): wave w -> rows w*4..+3, each quad
  // one row: 8 scalar cols per lane, 16-lane tree reduce.
  {
    int row = w * 4 + quad;
    float s1 = 0.f, s2 = 0.f;
    #pragma unroll
    for (int ci = 0; ci < 8; ++ci) {
      float v = fe[(size_t)(m0 + row) * DE + ci * 16 + sub];
      s1 += v;
      s2 += v * v;
    }
    #pragma unroll
    for (int off = 1; off < 16; off <<= 1) {
      s1 += __shfl_xor(s1, off);
      s2 += __shfl_xor(s2, off);
    }
    if (sub == 0) {
      float m = s1 * (1.0f / DE);
      float var = s2 * (1.0f / DE) - m * m;
      muL[row] = m;
      rsL[row] = rsqrtf(var + EPS);
    }
  }
  __syncthreads();
  f32x4 acc[2][2];  // [mi][ni]: ni 0 = shift tile, ni 1 = scale tile
  #pragma unroll
  for (int mi = 0; mi < 2; ++mi) {
    acc[mi][0] = (f32x4)(0.f);
    acc[mi][1] = (f32x4)(0.f);
  }
  for (int kc = 0; kc < 4; ++kc) {
    int ke = kc * 32 + quad * 8;
    bf16x8 ah[2], al[2];
    #pragma unroll
    for (int mi = 0; mi < 2; ++mi) {
      ah[mi] = *(const bf16x8*)&Xh[mi * 16 + sub][ke];
      al[mi] = *(const bf16x8*)&Xl[mi * 16 + sub][ke];
    }
    #pragma unroll
    for (int ni = 0; ni < 2; ++ni) {
      bf16x8 b = *(const bf16x8*)&We_bf[(size_t)(ni * DE + w * 16 + sub) * DE + ke];
      #pragma unroll
      for (int mi = 0; mi < 2; ++mi) {
        acc[mi][ni] = __builtin_amdgcn_mfma_f32_16x16x32_bf16(al[mi], b, acc[mi][ni], 0, 0, 0);
        acc[mi][ni] = __builtin_amdgcn_mfma_f32_16x16x32_bf16(ah[mi], b, acc[mi][ni], 0, 0, 0);
      }
    }
  }
  // epilogue
  {
    int c = w * 16 + sub;
    float bsh = b_e[c];
    float bsc = b_e[DE + c];
    #pragma unroll
    for (int mi = 0; mi < 2; ++mi)
      #pragma unroll
      for (int j = 0; j < 4; ++j) {
        int row = mi * 16 + quad * 4 + j;
        size_t g = (size_t)(m0 + row) * DE + c;
        float v = fe[g];
        float sh = acc[mi][0][j] + bsh;
        float sc = acc[mi][1][j] + bsc;
        fe_out[g] = (v - muL[row]) * rsL[row] * (1.0f + sc) + sh;
      }
  }
}

// ------ fused per-graph kernel: fg LN + s, pos segment-norm + out ---------
__global__ __launch_bounds__(256) void k_fg_pos(
    const float* __restrict__ fg, const float* __restrict__ g_gamma,
    const float* __restrict__ g_beta, const float* __restrict__ W_pos,
    const float* __restrict__ b_pos, const float* __restrict__ fv_pos,
    const int* __restrict__ node_gid, float* __restrict__ fg_out,
    float* __restrict__ pos_out) {
  const int g = blockIdx.x, t = threadIdx.x;
  const int lane = t & 63, wave = t >> 6;
  __shared__ float p1[4], p2[4], p3[4];
  __shared__ float px[4], py[4], pz[4], pq[4];
  // ---- graph LN + s ----
  float x = fg[g * DG + t];
  float sv = silu_f(x) * W_pos[t];
  float s1 = x, s2 = x * x, s3 = sv;
  #pragma unroll
  for (int off = 32; off > 0; off >>= 1) {
    s1 += __shfl_xor(s1, off);
    s2 += __shfl_xor(s2, off);
    s3 += __shfl_xor(s3, off);
  }
  if (lane == 0) { p1[wave] = s1; p2[wave] = s2; p3[wave] = s3; }
  __syncthreads();
  s1 = p1[0] + p1[1] + p1[2] + p1[3];
  s2 = p2[0] + p2[1] + p2[2] + p2[3];
  float mu = s1 * (1.0f / DG);
  float var = s2 * (1.0f / DG) - mu * mu;
  float rstd = rsqrtf(var + EPS);
  fg_out[g * DG + t] = (x - mu) * rstd * g_gamma[t] + g_beta[t];
  float s_own = (p3[0] + p3[1] + p3[2] + p3[3]) + b_pos[0];  // s for graph g
  // ---- position ----
  const int i = g * 256 + t;
  const int gid = node_gid[i];
  float vx = fv_pos[3 * i + 0];
  float vy = fv_pos[3 * i + 1];
  float vz = fv_pos[3 * i + 2];
  if (__syncthreads_and(gid == g)) {
    float rx = vx, ry = vy, rz = vz, rq = vx * vx + vy * vy + vz * vz;
    #pragma unroll
    for (int off = 32; off > 0; off >>= 1) {
      rx += __shfl_xor(rx, off);
      ry += __shfl_xor(ry, off);
      rz += __shfl_xor(rz, off);
      rq += __shfl_xor(rq, off);
    }
    if (lane == 0) { px[wave] = rx; py[wave] = ry; pz[wave] = rz; pq[wave] = rq; }
    __syncthreads();
    float sx = px[0] + px[1] + px[2] + px[3];
    float sy = py[0] + py[1] + py[2] + py[3];
    float sz = pz[0] + pz[1] + pz[2] + pz[3];
    float sq = pq[0] + pq[1] + pq[2] + pq[3];
    float ic = 1.0f / 256.0f;
    float mx = sx * ic, my = sy * ic, mz = sz * ic;
    float cq = fmaxf(sq - 256.0f * (mx * mx + my * my + mz * mz), 0.0f);
    float rms = sqrtf(cq / (256.0f * 3.0f) + EPS);
    float sc = (1.0f + s_own) / rms;
    pos_out[3 * i + 0] = (vx - mx) * sc;
    pos_out[3 * i + 1] = (vy - my) * sc;
    pos_out[3 * i + 2] = (vz - mz) * sc;
  } else {
    // slow but fully general fallback: scan all nodes of this thread's graph
    float sx = 0.f, sy = 0.f, sz = 0.f, sq = 0.f, cnt = 0.f;
    for (int j = 0; j < N_NODES; ++j) {
      if (node_gid[j] == gid) {
        float ax = fv_pos[3 * j + 0];
        float ay = fv_pos[3 * j + 1];
        float az = fv_pos[3 * j + 2];
        sx += ax; sy += ay; sz += az;
        sq += ax * ax + ay * ay + az * az;
        cnt += 1.0f;
      }
    }
    float ic = 1.0f / fmaxf(cnt, 1.0f);
    float mx = sx * ic, my = sy * ic, mz = sz * ic;
    float cq = fmaxf(sq - cnt * (mx * mx + my * my + mz * mz), 0.0f);
    float rms = sqrtf(cq / (cnt * 3.0f) + EPS);
    float sg = 0.f;
    for (int c = 0; c < DG; ++c) sg += silu_f(fg[gid * DG + c]) * W_pos[c];
    float sc = (1.0f + sg + b_pos[0]) / rms;
    pos_out[3 * i + 0] = (vx - mx) * sc;
    pos_out[3 * i + 1] = (vy - my) * sc;
    pos_out[3 * i + 2] = (vz - mz) * sc;
  }
}

extern "C" void kernel_launch(void* const* d_in, const int* in_sizes, int n_in,
                              void* d_out, int out_size, void* d_ws,
                              size_t ws_size, hipStream_t stream) {
  const float* fv = (const float*)d_in[0];
  const float* fe = (const float*)d_in[1];
  const float* fg = (const float*)d_in[2];
  const float* fv_pos = (const float*)d_in[3];
  const float* fv_c = (const float*)d_in[4];
  const float* fe_c = (const float*)d_in[5];
  const float* fv_pos_c = (const float*)d_in[6];
  const float* W_v = (const float*)d_in[7];
  const float* b_v = (const float*)d_in[8];
  const float* W_vpos = (const float*)d_in[9];
  const float* b_vpos = (const float*)d_in[10];
  const float* W_e = (const float*)d_in[11];
  const float* b_e = (const float*)d_in[12];
  const float* g_gamma = (const float*)d_in[13];
  const float* g_beta = (const float*)d_in[14];
  const float* W_pos = (const float*)d_in[15];
  const float* b_pos = (const float*)d_in[16];
  const int* src = (const int*)d_in[17];
  const int* dst = (const int*)d_in[18];
  const int* node_gid = (const int*)d_in[19];

  float* out = (float*)d_out;
  float* fv_out = out;
  float* fe_out = fv_out + (size_t)N_NODES * DV;
  float* fg_out = fe_out + (size_t)N_EDGES * DE;
  float* pos_out = fg_out + (size_t)N_GRAPH * DG;

  char* ws = (char*)d_ws;
  ushort_t* fvp_bf = (ushort_t*)ws;                                  // 16.8 MB
  ushort_t* Wv_bf = (ushort_t*)(ws + 16777216);                      // 256 KB
  ushort_t* We_bf = (ushort_t*)(ws + 16777216 + 262144);             // 64 KB
  ushort_t* Wvpos_bf = (ushort_t*)(ws + 16777216 + 262144 + 65536);  // 64 KB

  k_prep<<<192, 256, 0, stream>>>(W_v, W_e, W_vpos, Wv_bf, We_bf, Wvpos_bf);
  k_fvp<<<N_NODES / 32, 512, 0, stream>>>(fv_pos_c, Wvpos_bf, b_vpos, fvp_bf);
  k_node<<<N_NODES / 32, 512, 0, stream>>>(fv, fv_c, fv_pos_c, Wv_bf, b_v, fv_out);
  k_edge<<<N_EDGES / 32, 512, 0, stream>>>(fe, fe_c, fvp_bf, src, dst, We_bf,
                                           b_e, fe_out);
  k_fg_pos<<<N_GRAPH, 256, 0, stream>>>(fg, g_gamma, g_beta, W_pos, b_pos,
                                        fv_pos, node_gid, fg_out, pos_out);
}

// Round 11
// 265.653 us; speedup vs baseline: 1.1845x; 1.0728x over previous
//
#include <hip/hip_runtime.h>

#define N_NODES 65536
#define N_EDGES 262144
#define N_GRAPH 256
#define DV 256
#define DE 128
#define DG 256
#define EPS 1e-5f

typedef __bf16 bf16_t;
typedef bf16_t bf16x8 __attribute__((ext_vector_type(8)));
typedef float f32x4 __attribute__((ext_vector_type(4)));
typedef unsigned short ushort_t;

__device__ __forceinline__ float silu_f(float x) {
  return x / (1.0f + __expf(-x));
}
__device__ __forceinline__ ushort_t f2bf(float f) {
  bf16_t h = (bf16_t)f;  // RTNE (v_cvt_pk_bf16_f32) — bit-identical to manual
  return __builtin_bit_cast(ushort_t, h);
}
__device__ __forceinline__ float bf2f(ushort_t h) {
  return __uint_as_float(((unsigned int)h) << 16);
}
__device__ __forceinline__ void split_bf(float x, ushort_t& hi, ushort_t& lo) {
  hi = f2bf(x);
  lo = f2bf(x - bf2f(hi));
}
__device__ __forceinline__ void wave_reduce2(float& s1, float& s2) {
  #pragma unroll
  for (int off = 32; off > 0; off >>= 1) {
    s1 += __shfl_xor(s1, off);
    s2 += __shfl_xor(s2, off);
  }
}

// ---------------- prep: convert weights f32 -> bf16 (row-major [N][K]) -----
__global__ __launch_bounds__(256) void k_prep(
    const float* __restrict__ W_v, const float* __restrict__ W_e,
    const float* __restrict__ W_vpos, ushort_t* __restrict__ Wv_bf,
    ushort_t* __restrict__ We_bf, ushort_t* __restrict__ Wvpos_bf) {
  int idx = blockIdx.x * 256 + threadIdx.x;  // float4 group id, 49152 total
  const float* s;
  ushort_t* d;
  int o;
  if (idx < 32768) { s = W_v; d = Wv_bf; o = idx; }
  else if (idx < 40960) { s = W_e; d = We_bf; o = idx - 32768; }
  else { s = W_vpos; d = Wvpos_bf; o = idx - 40960; }
  float4 v = *(const float4*)&s[(size_t)o * 4];
  ushort4 r;
  r.x = f2bf(v.x); r.y = f2bf(v.y); r.z = f2bf(v.z); r.w = f2bf(v.w);
  *(ushort4*)&d[(size_t)o * 4] = r;
}

// ---------------- fvp = fv_pos_c @ W_vpos^T + b  -> bf16 [N,128] -----------
// M-tile 32, 8 waves: wave w -> rows (w&1)*16, cols (w>>1)*32 (hi/lo kept)
__global__ __launch_bounds__(512) void k_fvp(
    const float* __restrict__ fv_pos_c, const ushort_t* __restrict__ Wvpos_bf,
    const float* __restrict__ b_vpos, ushort_t* __restrict__ fvp_bf) {
  __shared__ __align__(16) ushort_t Xh[32][264];
  __shared__ __align__(16) ushort_t Xl[32][264];
  const int tid = threadIdx.x;
  const int l = tid & 63, w = tid >> 6;
  const int m0 = blockIdx.x * 32;
  #pragma unroll
  for (int i = 0; i < 4; ++i) {
    int idx = i * 512 + tid;          // 0..2047
    int r = idx >> 6, c4 = idx & 63;  // 32 rows x 64 groups
    float4 v = *(const float4*)&fv_pos_c[(size_t)(m0 + r) * DV + c4 * 4];
    ushort4 h, lo;
    split_bf(v.x, h.x, lo.x);
    split_bf(v.y, h.y, lo.y);
    split_bf(v.z, h.z, lo.z);
    split_bf(v.w, h.w, lo.w);
    *(ushort4*)&Xh[r][c4 * 4] = h;
    *(ushort4*)&Xl[r][c4 * 4] = lo;
  }
  __syncthreads();
  f32x4 acc[2];
  acc[0] = (f32x4)(0.f);
  acc[1] = (f32x4)(0.f);
  const int mrow = (w & 1) * 16;
  const int ncol0 = (w >> 1) * 32;
  const int arow = mrow + (l & 15);
  for (int kc = 0; kc < 8; ++kc) {
    int ke = kc * 32 + (l >> 4) * 8;
    bf16x8 ah = *(const bf16x8*)&Xh[arow][ke];
    bf16x8 al = *(const bf16x8*)&Xl[arow][ke];
    #pragma unroll
    for (int ni = 0; ni < 2; ++ni) {
      bf16x8 b = *(const bf16x8*)&Wvpos_bf[(size_t)(ncol0 + ni * 16 + (l & 15)) * DV + ke];
      acc[ni] = __builtin_amdgcn_mfma_f32_16x16x32_bf16(al, b, acc[ni], 0, 0, 0);
      acc[ni] = __builtin_amdgcn_mfma_f32_16x16x32_bf16(ah, b, acc[ni], 0, 0, 0);
    }
  }
  #pragma unroll
  for (int ni = 0; ni < 2; ++ni) {
    int col = ncol0 + ni * 16 + (l & 15);
    float bias = b_vpos[col];
    #pragma unroll
    for (int j = 0; j < 4; ++j) {
      int row = m0 + mrow + (l >> 4) * 4 + j;
      fvp_bf[(size_t)row * DE + col] = f2bf(acc[ni][j] + bias);
    }
  }
}

// ------- node path: mod_v MFMA GEMM fused with LN(fv) -> fv_out -----------
// M-tile 32, N=512, K=256. Single-pass bf16 X (no lo-half). Wave w owns
// shift cols [w*32,+32) AND scale cols [256+w*32,+32).
__global__ __launch_bounds__(512) void k_node(
    const float* __restrict__ fv, const float* __restrict__ fv_c,
    const float* __restrict__ fv_pos_c, const ushort_t* __restrict__ Wv_bf,
    const float* __restrict__ b_v, float* __restrict__ fv_out) {
  __shared__ __align__(16) ushort_t Xh[32][264];
  __shared__ float muL[32], rsL[32];
  const int tid = threadIdx.x;
  const int l = tid & 63, w = tid >> 6;
  const int m0 = blockIdx.x * 32;
  // stage X = bf16(silu(fv_c + fv_pos_c))
  #pragma unroll
  for (int i = 0; i < 4; ++i) {
    int idx = i * 512 + tid;
    int r = idx >> 6, c4 = idx & 63;
    size_t g = (size_t)(m0 + r) * DV + c4 * 4;
    float4 a = *(const float4*)&fv_c[g];
    float4 b = *(const float4*)&fv_pos_c[g];
    ushort4 h;
    h.x = f2bf(silu_f(a.x + b.x));
    h.y = f2bf(silu_f(a.y + b.y));
    h.z = f2bf(silu_f(a.z + b.z));
    h.w = f2bf(silu_f(a.w + b.w));
    *(ushort4*)&Xh[r][c4 * 4] = h;
  }
  // LN stats: wave w handles rows w*4..+3
  #pragma unroll
  for (int rr = 0; rr < 4; ++rr) {
    int row = w * 4 + rr;
    float4 v = *(const float4*)&fv[(size_t)(m0 + row) * DV + l * 4];
    float s1 = v.x + v.y + v.z + v.w;
    float s2 = v.x * v.x + v.y * v.y + v.z * v.z + v.w * v.w;
    wave_reduce2(s1, s2);
    if (l == 0) {
      float mu = s1 * (1.0f / DV);
      float var = s2 * (1.0f / DV) - mu * mu;
      muL[row] = mu;
      rsL[row] = rsqrtf(var + EPS);
    }
  }
  __syncthreads();
  f32x4 acc[2][4];  // [mi][ni]: ni 0,1 = shift tiles, ni 2,3 = scale tiles
  #pragma unroll
  for (int mi = 0; mi < 2; ++mi)
    #pragma unroll
    for (int ni = 0; ni < 4; ++ni) acc[mi][ni] = (f32x4)(0.f);
  int ncol[4];
  ncol[0] = w * 32;
  ncol[1] = w * 32 + 16;
  ncol[2] = DV + w * 32;
  ncol[3] = DV + w * 32 + 16;
  for (int kc = 0; kc < 8; ++kc) {
    int ke = kc * 32 + (l >> 4) * 8;
    bf16x8 ah[2];
    #pragma unroll
    for (int mi = 0; mi < 2; ++mi)
      ah[mi] = *(const bf16x8*)&Xh[mi * 16 + (l & 15)][ke];
    #pragma unroll
    for (int ni = 0; ni < 4; ++ni) {
      bf16x8 b = *(const bf16x8*)&Wv_bf[(size_t)(ncol[ni] + (l & 15)) * DV + ke];
      #pragma unroll
      for (int mi = 0; mi < 2; ++mi)
        acc[mi][ni] = __builtin_amdgcn_mfma_f32_16x16x32_bf16(ah[mi], b, acc[mi][ni], 0, 0, 0);
    }
  }
  // epilogue: in-register modulation
  #pragma unroll
  for (int ni2 = 0; ni2 < 2; ++ni2) {
    int c = w * 32 + ni2 * 16 + (l & 15);
    float bsh = b_v[c];
    float bsc = b_v[DV + c];
    #pragma unroll
    for (int mi = 0; mi < 2; ++mi)
      #pragma unroll
      for (int j = 0; j < 4; ++j) {
        int row = mi * 16 + (l >> 4) * 4 + j;
        size_t g = (size_t)(m0 + row) * DV + c;
        float v = fv[g];
        float sh = acc[mi][ni2][j] + bsh;
        float sc = acc[mi][ni2 + 2][j] + bsc;
        fv_out[g] = (v - muL[row]) * rsL[row] * (1.0f + sc) + sh;
      }
  }
}

// ------- edge path: gather + mod_e MFMA GEMM fused with LN(fe) ------------
// M-tile 64 (R7 shape), N=256, K=128. Single-pass bf16 X (no lo-half).
// Wave w owns shift cols [w*16,+16) and scale cols [128+w*16,+16).
__global__ __launch_bounds__(512) void k_edge(
    const float* __restrict__ fe, const float* __restrict__ fe_c,
    const ushort_t* __restrict__ fvp_bf, const int* __restrict__ src,
    const int* __restrict__ dst, const ushort_t* __restrict__ We_bf,
    const float* __restrict__ b_e, float* __restrict__ fe_out) {
  __shared__ __align__(16) ushort_t Xh[64][136];
  __shared__ float muL[64], rsL[64];
  const int tid = threadIdx.x;
  const int l = tid & 63, w = tid >> 6;
  const int m0 = blockIdx.x * 64;
  const int sub = l & 15, quad = l >> 4;
  // stage X = bf16(silu(fe_c + fvp[src] + fvp[dst]))
  #pragma unroll
  for (int i = 0; i < 4; ++i) {
    int idx = i * 512 + tid;          // 0..2047
    int r = idx >> 5, c4 = idx & 31;  // 64 rows x 32 groups
    int sr = src[m0 + r], dr = dst[m0 + r];
    float4 a = *(const float4*)&fe_c[(size_t)(m0 + r) * DE + c4 * 4];
    ushort4 p = *(const ushort4*)&fvp_bf[(size_t)sr * DE + c4 * 4];
    ushort4 q = *(const ushort4*)&fvp_bf[(size_t)dr * DE + c4 * 4];
    ushort4 h;
    h.x = f2bf(silu_f(a.x + bf2f(p.x) + bf2f(q.x)));
    h.y = f2bf(silu_f(a.y + bf2f(p.y) + bf2f(q.y)));
    h.z = f2bf(silu_f(a.z + bf2f(p.z) + bf2f(q.z)));
    h.w = f2bf(silu_f(a.w + bf2f(p.w) + bf2f(q.w)));
    *(ushort4*)&Xh[r][c4 * 4] = h;
  }
  // LN stats (quad-based, R5/R7 numerics): wave w -> rows w*8..+7, each quad
  // handles 2 rows, 8 scalar cols per lane, 16-lane tree reduce.
  #pragma unroll
  for (int j2 = 0; j2 < 2; ++j2) {
    int row = w * 8 + quad * 2 + j2;
    float s1 = 0.f, s2 = 0.f;
    #pragma unroll
    for (int ci = 0; ci < 8; ++ci) {
      float v = fe[(size_t)(m0 + row) * DE + ci * 16 + sub];
      s1 += v;
      s2 += v * v;
    }
    #pragma unroll
    for (int off = 1; off < 16; off <<= 1) {
      s1 += __shfl_xor(s1, off);
      s2 += __shfl_xor(s2, off);
    }
    if (sub == 0) {
      float m = s1 * (1.0f / DE);
      float var = s2 * (1.0f / DE) - m * m;
      muL[row] = m;
      rsL[row] = rsqrtf(var + EPS);
    }
  }
  __syncthreads();
  f32x4 acc[4][2];  // [mi][ni]: ni 0 = shift tile, ni 1 = scale tile
  #pragma unroll
  for (int mi = 0; mi < 4; ++mi) {
    acc[mi][0] = (f32x4)(0.f);
    acc[mi][1] = (f32x4)(0.f);
  }
  for (int kc = 0; kc < 4; ++kc) {
    int ke = kc * 32 + quad * 8;
    bf16x8 ah[4];
    #pragma unroll
    for (int mi = 0; mi < 4; ++mi)
      ah[mi] = *(const bf16x8*)&Xh[mi * 16 + sub][ke];
    #pragma unroll
    for (int ni = 0; ni < 2; ++ni) {
      bf16x8 b = *(const bf16x8*)&We_bf[(size_t)(ni * DE + w * 16 + sub) * DE + ke];
      #pragma unroll
      for (int mi = 0; mi < 4; ++mi)
        acc[mi][ni] = __builtin_amdgcn_mfma_f32_16x16x32_bf16(ah[mi], b, acc[mi][ni], 0, 0, 0);
    }
  }
  // epilogue
  {
    int c = w * 16 + sub;
    float bsh = b_e[c];
    float bsc = b_e[DE + c];
    #pragma unroll
    for (int mi = 0; mi < 4; ++mi)
      #pragma unroll
      for (int j = 0; j < 4; ++j) {
        int row = mi * 16 + quad * 4 + j;
        size_t g = (size_t)(m0 + row) * DE + c;
        float v = fe[g];
        float sh = acc[mi][0][j] + bsh;
        float sc = acc[mi][1][j] + bsc;
        fe_out[g] = (v - muL[row]) * rsL[row] * (1.0f + sc) + sh;
      }
  }
}

// ------ fused per-graph kernel: fg LN + s, pos segment-norm + out ---------
__global__ __launch_bounds__(256) void k_fg_pos(
    const float* __restrict__ fg, const float* __restrict__ g_gamma,
    const float* __restrict__ g_beta, const float* __restrict__ W_pos,
    const float* __restrict__ b_pos, const float* __restrict__ fv_pos,
    const int* __restrict__ node_gid, float* __restrict__ fg_out,
    float* __restrict__ pos_out) {
  const int g = blockIdx.x, t = threadIdx.x;
  const int lane = t & 63, wave = t >> 6;
  __shared__ float p1[4], p2[4], p3[4];
  __shared__ float px[4], py[4], pz[4], pq[4];
  // ---- graph LN + s ----
  float x = fg[g * DG + t];
  float sv = silu_f(x) * W_pos[t];
  float s1 = x, s2 = x * x, s3 = sv;
  #pragma unroll
  for (int off = 32; off > 0; off >>= 1) {
    s1 += __shfl_xor(s1, off);
    s2 += __shfl_xor(s2, off);
    s3 += __shfl_xor(s3, off);
  }
  if (lane == 0) { p1[wave] = s1; p2[wave] = s2; p3[wave] = s3; }
  __syncthreads();
  s1 = p1[0] + p1[1] + p1[2] + p1[3];
  s2 = p2[0] + p2[1] + p2[2] + p2[3];
  float mu = s1 * (1.0f / DG);
  float var = s2 * (1.0f / DG) - mu * mu;
  float rstd = rsqrtf(var + EPS);
  fg_out[g * DG + t] = (x - mu) * rstd * g_gamma[t] + g_beta[t];
  float s_own = (p3[0] + p3[1] + p3[2] + p3[3]) + b_pos[0];  // s for graph g
  // ---- position ----
  const int i = g * 256 + t;
  const int gid = node_gid[i];
  float vx = fv_pos[3 * i + 0];
  float vy = fv_pos[3 * i + 1];
  float vz = fv_pos[3 * i + 2];
  if (__syncthreads_and(gid == g)) {
    float rx = vx, ry = vy, rz = vz, rq = vx * vx + vy * vy + vz * vz;
    #pragma unroll
    for (int off = 32; off > 0; off >>= 1) {
      rx += __shfl_xor(rx, off);
      ry += __shfl_xor(ry, off);
      rz += __shfl_xor(rz, off);
      rq += __shfl_xor(rq, off);
    }
    if (lane == 0) { px[wave] = rx; py[wave] = ry; pz[wave] = rz; pq[wave] = rq; }
    __syncthreads();
    float sx = px[0] + px[1] + px[2] + px[3];
    float sy = py[0] + py[1] + py[2] + py[3];
    float sz = pz[0] + pz[1] + pz[2] + pz[3];
    float sq = pq[0] + pq[1] + pq[2] + pq[3];
    float ic = 1.0f / 256.0f;
    float mx = sx * ic, my = sy * ic, mz = sz * ic;
    float cq = fmaxf(sq - 256.0f * (mx * mx + my * my + mz * mz), 0.0f);
    float rms = sqrtf(cq / (256.0f * 3.0f) + EPS);
    float sc = (1.0f + s_own) / rms;
    pos_out[3 * i + 0] = (vx - mx) * sc;
    pos_out[3 * i + 1] = (vy - my) * sc;
    pos_out[3 * i + 2] = (vz - mz) * sc;
  } else {
    // slow but fully general fallback: scan all nodes of this thread's graph
    float sx = 0.f, sy = 0.f, sz = 0.f, sq = 0.f, cnt = 0.f;
    for (int j = 0; j < N_NODES; ++j) {
      if (node_gid[j] == gid) {
        float ax = fv_pos[3 * j + 0];
        float ay = fv_pos[3 * j + 1];
        float az = fv_pos[3 * j + 2];
        sx += ax; sy += ay; sz += az;
        sq += ax * ax + ay * ay + az * az;
        cnt += 1.0f;
      }
    }
    float ic = 1.0f / fmaxf(cnt, 1.0f);
    float mx = sx * ic, my = sy * ic, mz = sz * ic;
    float cq = fmaxf(sq - cnt * (mx * mx + my * my + mz * mz), 0.0f);
    float rms = sqrtf(cq / (cnt * 3.0f) + EPS);
    float sg = 0.f;
    for (int c = 0; c < DG; ++c) sg += silu_f(fg[gid * DG + c]) * W_pos[c];
    float sc = (1.0f + sg + b_pos[0]) / rms;
    pos_out[3 * i + 0] = (vx - mx) * sc;
    pos_out[3 * i + 1] = (vy - my) * sc;
    pos_out[3 * i + 2] = (vz - mz) * sc;
  }
}

extern "C" void kernel_launch(void* const* d_in, const int* in_sizes, int n_in,
                              void* d_out, int out_size, void* d_ws,
                              size_t ws_size, hipStream_t stream) {
  const float* fv = (const float*)d_in[0];
  const float* fe = (const float*)d_in[1];
  const float* fg = (const float*)d_in[2];
  const float* fv_pos = (const float*)d_in[3];
  const float* fv_c = (const float*)d_in[4];
  const float* fe_c = (const float*)d_in[5];
  const float* fv_pos_c = (const float*)d_in[6];
  const float* W_v = (const float*)d_in[7];
  const float* b_v = (const float*)d_in[8];
  const float* W_vpos = (const float*)d_in[9];
  const float* b_vpos = (const float*)d_in[10];
  const float* W_e = (const float*)d_in[11];
  const float* b_e = (const float*)d_in[12];
  const float* g_gamma = (const float*)d_in[13];
  const float* g_beta = (const float*)d_in[14];
  const float* W_pos = (const float*)d_in[15];
  const float* b_pos = (const float*)d_in[16];
  const int* src = (const int*)d_in[17];
  const int* dst = (const int*)d_in[18];
  const int* node_gid = (const int*)d_in[19];

  float* out = (float*)d_out;
  float* fv_out = out;
  float* fe_out = fv_out + (size_t)N_NODES * DV;
  float* fg_out = fe_out + (size_t)N_EDGES * DE;
  float* pos_out = fg_out + (size_t)N_GRAPH * DG;

  char* ws = (char*)d_ws;
  ushort_t* fvp_bf = (ushort_t*)ws;                                  // 16.8 MB
  ushort_t* Wv_bf = (ushort_t*)(ws + 16777216);                      // 256 KB
  ushort_t* We_bf = (ushort_t*)(ws + 16777216 + 262144);             // 64 KB
  ushort_t* Wvpos_bf = (ushort_t*)(ws + 16777216 + 262144 + 65536);  // 64 KB

  k_prep<<<192, 256, 0, stream>>>(W_v, W_e, W_vpos, Wv_bf, We_bf, Wvpos_bf);
  k_fvp<<<N_NODES / 32, 512, 0, stream>>>(fv_pos_c, Wvpos_bf, b_vpos, fvp_bf);
  k_node<<<N_NODES / 32, 512, 0, stream>>>(fv, fv_c, fv_pos_c, Wv_bf, b_v, fv_out);
  k_edge<<<N_EDGES / 64, 512, 0, stream>>>(fe, fe_c, fvp_bf, src, dst, We_bf,
                                           b_e, fe_out);
  k_fg_pos<<<N_GRAPH, 256, 0, stream>>>(fg, g_gamma, g_beta, W_pos, b_pos,
                                        fv_pos, node_gid, fg_out, pos_out);
}